// Round 7
// baseline (173.335 us; speedup 1.0000x reference)
//
#include <hip/hip_runtime.h>

// AttentionPITF: B=16384, K=256, M=50.
// Round 7 (= R6 with macro-hygiene fix: DOT4/HACC macros -> inline fns):
//  - attn: transposed score layout — 4 m's/iter, one per 16-lane group,
//    4-level reduce (was 6-level full-wave butterfly per m), exp 50->13.
//  - tagh_mfma stages A from f32 tagU directly (cvt in-kernel) and emits the
//    u8 tagU halves of comb from staging regs -> cvt_pack kernel deleted.
//  - mix epilogue reads ut/nut as u8 from comb (offsets cancel in the diff).

#define KDIM 256
#define MHIST 50
#define XROW 54
#define KFOLD 768

#define QS    (1.0f / 2048.0f)   // u8 quant scale
#define QINV  2048.0f

typedef __attribute__((ext_vector_type(8))) short bf16x8;
typedef __attribute__((ext_vector_type(4))) float f32x4;

__device__ __forceinline__ unsigned short f2bf(float f) {
    union { float f; unsigned int i; } v; v.f = f;
    unsigned int x = v.i;
    x += 0x7fffu + ((x >> 16) & 1u);          // RNE
    return (unsigned short)(x >> 16);
}
__device__ __forceinline__ unsigned int pack2bf(float a, float b) {
    return (unsigned int)f2bf(a) | ((unsigned int)f2bf(b) << 16);
}
__device__ __forceinline__ unsigned int quq(float v) {
    int q = (int)rintf(v * QINV) + 128;
    return (unsigned int)(q < 0 ? 0 : (q > 255 ? 255 : q));
}
__device__ __forceinline__ float dot4u8(unsigned int w, const float4& u) {
    return (float)(w & 255u)         * u.x + (float)((w >> 8) & 255u)  * u.y +
           (float)((w >> 16) & 255u) * u.z + (float)(w >> 24)          * u.w;
}
__device__ __forceinline__ void haccu8(float4& hv, unsigned int w, float e) {
    hv.x = fmaf(e, (float)(w & 255u),         hv.x);
    hv.y = fmaf(e, (float)((w >> 8) & 255u),  hv.y);
    hv.z = fmaf(e, (float)((w >> 16) & 255u), hv.z);
    hv.w = fmaf(e, (float)(w >> 24),          hv.w);
}

#define GLOAD16(g, l)                                                        \
    __builtin_amdgcn_global_load_lds(                                        \
        (const __attribute__((address_space(1))) void*)(g),                  \
        (__attribute__((address_space(3))) void*)(l), 16, 0, 0)

__device__ __forceinline__ f32x4 mfma16(bf16x8 a, bf16x8 b, f32x4 c) {
    return __builtin_amdgcn_mfma_f32_16x16x32_bf16(a, b, c, 0, 0, 0);
}

// ---------------- prep ----------------------------------------------------
__global__ __launch_bounds__(256) void cvt_kernel(
    const float* __restrict__ src, unsigned short* __restrict__ dst, int n4)
{
    int i = blockIdx.x * 256 + threadIdx.x;
    if (i >= n4) return;
    float4 v = ((const float4*)src)[i];
    ushort4 o;
    o.x = f2bf(v.x); o.y = f2bf(v.y); o.z = f2bf(v.z); o.w = f2bf(v.w);
    ((ushort4*)dst)[i] = o;
}

// Wfold[j][0:256]=W1+W3, [256:512]=W2-W3, [512:768]=W4  (from W_map[j][1024])
__global__ __launch_bounds__(256) void fold_kernel(
    const float* __restrict__ Wmap, unsigned short* __restrict__ Wf)
{
    int idx = blockIdx.x * 256 + threadIdx.x;   // < 256*768
    int j = idx / KFOLD, c = idx % KFOLD;
    int seg = c >> 8, k = c & 255;
    const float* row = Wmap + (size_t)j * 1024;
    float f;
    if (seg == 0)      f = row[k]       + row[512 + k];
    else if (seg == 1) f = row[256 + k] - row[512 + k];
    else               f = row[768 + k];
    Wf[idx] = f2bf(f);
}

// ---------------- Kernel A: tagH = relu(tagU @ W_att^T + b_att) -----------
// A staged from f32 tagU (in-kernel cvt); u8 tagU halves of comb written
// from the same staging registers (blockIdx.y==0 only).
__global__ __launch_bounds__(256) void tagh_mfma_kernel(
    const float* __restrict__ tagU,          // f32 [NT][256]
    const unsigned short* __restrict__ Bb,   // W_att bf16 [256][256]
    const float* __restrict__ batt,
    unsigned int* __restrict__ comb32,       // [NT][128] dwords
    int NT)
{
    __shared__ unsigned short As[128 * 32];
    __shared__ unsigned short Bs[128 * 32];
    const int tid = threadIdx.x;
    const int lane = tid & 63, wave = tid >> 6;
    const int wr = wave >> 1, wc = wave & 1;
    const int m0 = blockIdx.x * 128, n0 = blockIdx.y * 128;
    const int r = tid >> 1, kh = tid & 1;

    const int gm  = m0 + r;
    const int gmc = gm < NT ? gm : NT - 1;
    const float* arow = tagU + (size_t)gmc * KDIM + kh * 16;

    f32x4 acc[4][4] = {};

    for (int k0 = 0; k0 < KDIM; k0 += 32) {
        // B: global_load_lds (bf16)
#pragma unroll
        for (int p = 0; p < 2; ++p) {
            int s = tid + p * 256;
            int row = s >> 2, ch = s & 3;
            GLOAD16(Bb + ((size_t)(n0 + row) * KDIM + k0 + ch * 8), Bs + s * 8);
        }
        // A: f32 load -> cvt -> ds_write (16 elems/thread)
        const float4 f0 = *(const float4*)(arow + k0);
        const float4 f1 = *(const float4*)(arow + k0 + 4);
        const float4 f2 = *(const float4*)(arow + k0 + 8);
        const float4 f3 = *(const float4*)(arow + k0 + 12);
        uint4 w0, w1;
        w0.x = pack2bf(f0.x, f0.y); w0.y = pack2bf(f0.z, f0.w);
        w0.z = pack2bf(f1.x, f1.y); w0.w = pack2bf(f1.z, f1.w);
        w1.x = pack2bf(f2.x, f2.y); w1.y = pack2bf(f2.z, f2.w);
        w1.z = pack2bf(f3.x, f3.y); w1.w = pack2bf(f3.z, f3.w);
        *(uint4*)&As[r * 32 + kh * 16]     = w0;
        *(uint4*)&As[r * 32 + kh * 16 + 8] = w1;
        if (n0 == 0 && gm < NT) {
            const int cb = (k0 >> 2) + kh * 4;
            unsigned int* cp = comb32 + (size_t)gm * 128;
            cp[(cb + 0) * 2 + 1] = quq(f0.x) | (quq(f0.y) << 8) |
                                   (quq(f0.z) << 16) | (quq(f0.w) << 24);
            cp[(cb + 1) * 2 + 1] = quq(f1.x) | (quq(f1.y) << 8) |
                                   (quq(f1.z) << 16) | (quq(f1.w) << 24);
            cp[(cb + 2) * 2 + 1] = quq(f2.x) | (quq(f2.y) << 8) |
                                   (quq(f2.z) << 16) | (quq(f2.w) << 24);
            cp[(cb + 3) * 2 + 1] = quq(f3.x) | (quq(f3.y) << 8) |
                                   (quq(f3.z) << 16) | (quq(f3.w) << 24);
        }
        __syncthreads();
        bf16x8 af[4], bg[4];
#pragma unroll
        for (int m = 0; m < 4; ++m) {
            int ar = wr * 64 + m * 16 + (lane & 15);
            af[m] = *(const bf16x8*)&As[ar * 32 + (lane >> 4) * 8];
        }
#pragma unroll
        for (int n = 0; n < 4; ++n) {
            int br = wc * 64 + n * 16 + (lane & 15);
            bg[n] = *(const bf16x8*)&Bs[br * 32 + (lane >> 4) * 8];
        }
#pragma unroll
        for (int m = 0; m < 4; ++m)
#pragma unroll
            for (int n = 0; n < 4; ++n)
                acc[m][n] = mfma16(af[m], bg[n], acc[m][n]);
        __syncthreads();
    }

    unsigned char* comb = (unsigned char*)comb32;
#pragma unroll
    for (int n = 0; n < 4; ++n) {
        int col = n0 + wc * 64 + n * 16 + (lane & 15);
        float bias = batt[col];
        int boff = 8 * (col >> 2) + (col & 3);
#pragma unroll
        for (int m = 0; m < 4; ++m)
#pragma unroll
            for (int rr = 0; rr < 4; ++rr) {
                int grow = m0 + wr * 64 + m * 16 + (lane >> 4) * 4 + rr;
                if (grow < NT)
                    comb[(size_t)grow * 512 + boff] =
                        (unsigned char)quq(fmaxf(acc[m][n][rr] + bias, 0.f));
            }
    }
}

// ---------------- Kernel B: per-row attention, one wave per row -----------
// Transposed: 4 m's per iter, group g=lane>>4 owns m=4j+g, lane il=lane&15
// covers k=16*il..16*il+15 (2 x uint4 fused-chunk loads). 4-level reduce.
__global__ __launch_bounds__(256) void attn_kernel(
    const int* __restrict__ x,
    const float* __restrict__ userVecs,
    const float* __restrict__ itemVecs,
    const float* __restrict__ tagI,
    const unsigned int* __restrict__ comb32,  // [NT][128] dwords
    unsigned short* __restrict__ zA,          // [B][768] bf16: u, h, u*h
    float* __restrict__ r)
{
    const int tid  = threadIdx.x;
    const int wave = tid >> 6, lane = tid & 63;
    const int b    = blockIdx.x * 4 + wave;
    const int g    = lane >> 4, il = lane & 15;

    const int xv = x[(size_t)b * XROW + (lane < XROW ? lane : XROW - 1)];
    const int x0 = __shfl(xv, 0), x1 = __shfl(xv, 1);
    const int x2 = __shfl(xv, 2), x3 = __shfl(xv, 3);

    const float* up = userVecs + (size_t)x0 * KDIM + il * 16;
    const float4 uf0 = *(const float4*)(up);
    const float4 uf1 = *(const float4*)(up + 4);
    const float4 uf2 = *(const float4*)(up + 8);
    const float4 uf3 = *(const float4*)(up + 12);

    float4 hA = {0,0,0,0}, hB = {0,0,0,0}, hC = {0,0,0,0}, hD = {0,0,0,0};
    float ssum = 0.f;

#pragma unroll 2
    for (int j = 0; j < 13; ++j) {
        const int m = 4 * j + g;
        const int ms = m < MHIST - 1 ? m : MHIST - 1;
        const int t = __shfl(xv, 4 + ms);     // all lanes execute the shfl
        if (m < MHIST) {
            const unsigned int* cp = comb32 + (size_t)t * 128 + il * 8;
            const uint4 c0 = *(const uint4*)(cp);
            const uint4 c1 = *(const uint4*)(cp + 4);
            float d = dot4u8(c0.x, uf0) + dot4u8(c0.z, uf1) +
                      dot4u8(c1.x, uf2) + dot4u8(c1.z, uf3);
            d += __shfl_xor(d, 1);
            d += __shfl_xor(d, 2);
            d += __shfl_xor(d, 4);
            d += __shfl_xor(d, 8);
            const float e = __expf(d * QS);
            ssum += e;
            haccu8(hA, c0.y, e); haccu8(hB, c0.w, e);
            haccu8(hC, c1.y, e); haccu8(hD, c1.w, e);
        }
    }

    // combine h and ssum across the 4 groups (xor 16, 32)
#define COMB(v) v += __shfl_xor(v, 16); v += __shfl_xor(v, 32);
    COMB(hA.x) COMB(hA.y) COMB(hA.z) COMB(hA.w)
    COMB(hB.x) COMB(hB.y) COMB(hB.z) COMB(hB.w)
    COMB(hC.x) COMB(hC.y) COMB(hC.z) COMB(hC.w)
    COMB(hD.x) COMB(hD.y) COMB(hD.z) COMB(hD.w)
    COMB(ssum)
#undef COMB

    const float sc = QS / ssum;
    const float c128 = 128.0f * QS;
    hA.x = hA.x * sc - c128; hA.y = hA.y * sc - c128;
    hA.z = hA.z * sc - c128; hA.w = hA.w * sc - c128;
    hB.x = hB.x * sc - c128; hB.y = hB.y * sc - c128;
    hB.z = hB.z * sc - c128; hB.w = hB.w * sc - c128;
    hC.x = hC.x * sc - c128; hC.y = hC.y * sc - c128;
    hC.z = hC.z * sc - c128; hC.w = hC.w * sc - c128;
    hD.x = hD.x * sc - c128; hD.y = hD.y * sc - c128;
    hD.z = hD.z * sc - c128; hD.w = hD.w * sc - c128;

    // z = [u, h, u*h] bf16; group 0/1/2 writes one 256-elem segment each
    const size_t zb = (size_t)b * KFOLD;
    if (g == 0) {
        uint4 w;
        w.x = pack2bf(uf0.x, uf0.y); w.y = pack2bf(uf0.z, uf0.w);
        w.z = pack2bf(uf1.x, uf1.y); w.w = pack2bf(uf1.z, uf1.w);
        *(uint4*)&zA[zb + il * 16] = w;
        w.x = pack2bf(uf2.x, uf2.y); w.y = pack2bf(uf2.z, uf2.w);
        w.z = pack2bf(uf3.x, uf3.y); w.w = pack2bf(uf3.z, uf3.w);
        *(uint4*)&zA[zb + il * 16 + 8] = w;
    } else if (g == 1) {
        uint4 w;
        w.x = pack2bf(hA.x, hA.y); w.y = pack2bf(hA.z, hA.w);
        w.z = pack2bf(hB.x, hB.y); w.w = pack2bf(hB.z, hB.w);
        *(uint4*)&zA[zb + 256 + il * 16] = w;
        w.x = pack2bf(hC.x, hC.y); w.y = pack2bf(hC.z, hC.w);
        w.z = pack2bf(hD.x, hD.y); w.w = pack2bf(hD.z, hD.w);
        *(uint4*)&zA[zb + 256 + il * 16 + 8] = w;
    } else if (g == 2) {
        uint4 w;
        w.x = pack2bf(uf0.x * hA.x, uf0.y * hA.y);
        w.y = pack2bf(uf0.z * hA.z, uf0.w * hA.w);
        w.z = pack2bf(uf1.x * hB.x, uf1.y * hB.y);
        w.w = pack2bf(uf1.z * hB.z, uf1.w * hB.w);
        *(uint4*)&zA[zb + 512 + il * 16] = w;
        w.x = pack2bf(uf2.x * hC.x, uf2.y * hC.y);
        w.y = pack2bf(uf2.z * hC.z, uf2.w * hC.w);
        w.z = pack2bf(uf3.x * hD.x, uf3.y * hD.y);
        w.w = pack2bf(uf3.z * hD.z, uf3.w * hD.w);
        *(uint4*)&zA[zb + 512 + il * 16 + 8] = w;
    }

    // r[b] = iv . (it - nit)   (f32, lane*4 layout)
    const float4 iv  = *(const float4*)&itemVecs[(size_t)x1 * KDIM + lane * 4];
    const float4 itv = *(const float4*)&tagI[(size_t)x2 * KDIM + lane * 4];
    const float4 niv = *(const float4*)&tagI[(size_t)x3 * KDIM + lane * 4];
    float part = iv.x * (itv.x - niv.x) + iv.y * (itv.y - niv.y) +
                 iv.z * (itv.z - niv.z) + iv.w * (itv.w - niv.w);
#pragma unroll
    for (int off = 32; off >= 1; off >>= 1) part += __shfl_xor(part, off);
    if (lane == 0) r[b] = part;
}

// ---------------- Kernel C: mix GEMM (bf16 MFMA) + fused dot --------------
__global__ __launch_bounds__(256) void mix_mfma_kernel(
    const unsigned short* __restrict__ Zb,   // [B][768] bf16
    const unsigned short* __restrict__ Wf,   // [256][768] bf16
    const float* __restrict__ bmap,
    const int* __restrict__ x,
    const unsigned int* __restrict__ comb32, // u8 table for ut/nut epilogue
    float* __restrict__ r,
    int Bn)
{
    __shared__ unsigned short As[128 * 32];
    __shared__ unsigned short Bs[128 * 32];
    __shared__ int xr2s[128], xr3s[128];

    const int tid = threadIdx.x;
    const int lane = tid & 63, wave = tid >> 6;
    const int wr = wave >> 1, wc = wave & 1;
    const int b0 = blockIdx.x * 128, n0 = blockIdx.y * 128;

    if (tid < 128) {
        int gb = b0 + tid;
        xr2s[tid] = x[(size_t)gb * XROW + 2];
        xr3s[tid] = x[(size_t)gb * XROW + 3];
    }

    f32x4 acc[4][4] = {};

    for (int k0 = 0; k0 < KFOLD; k0 += 32) {
#pragma unroll
        for (int p = 0; p < 2; ++p) {
            int s = tid + p * 256;
            int row = s >> 2, ch = s & 3;
            GLOAD16(Zb + ((size_t)(b0 + row) * KFOLD + k0 + ch * 8), As + s * 8);
            GLOAD16(Wf + ((size_t)(n0 + row) * KFOLD + k0 + ch * 8), Bs + s * 8);
        }
        __syncthreads();
        bf16x8 af[4], bg[4];
#pragma unroll
        for (int m = 0; m < 4; ++m) {
            int ar = wr * 64 + m * 16 + (lane & 15);
            af[m] = *(const bf16x8*)&As[ar * 32 + (lane >> 4) * 8];
        }
#pragma unroll
        for (int n = 0; n < 4; ++n) {
            int br = wc * 64 + n * 16 + (lane & 15);
            bg[n] = *(const bf16x8*)&Bs[br * 32 + (lane >> 4) * 8];
        }
#pragma unroll
        for (int m = 0; m < 4; ++m)
#pragma unroll
            for (int n = 0; n < 4; ++n)
                acc[m][n] = mfma16(af[m], bg[n], acc[m][n]);
        __syncthreads();
    }

    const unsigned char* comb = (const unsigned char*)comb32;
    int   offn[4];
    float bias[4];
#pragma unroll
    for (int n = 0; n < 4; ++n) {
        int col = n0 + wc * 64 + n * 16 + (lane & 15);
        bias[n] = bmap[col];
        offn[n] = 8 * (col >> 2) + 4 + (col & 3);   // u8 tagU byte in comb row
    }
#pragma unroll
    for (int m = 0; m < 4; ++m)
#pragma unroll
        for (int rr = 0; rr < 4; ++rr) {
            int rl = wr * 64 + m * 16 + (lane >> 4) * 4 + rr;
            const unsigned char* utp = comb + (size_t)xr2s[rl] * 512;
            const unsigned char* ntp = comb + (size_t)xr3s[rl] * 512;
            float p = 0.f;
#pragma unroll
            for (int n = 0; n < 4; ++n) {
                float mixv = fmaxf(acc[m][n][rr] + bias[n], 0.f);
                p += mixv * (float)((int)utp[offn[n]] - (int)ntp[offn[n]]);
            }
            p += __shfl_xor(p, 1);
            p += __shfl_xor(p, 2);
            p += __shfl_xor(p, 4);
            p += __shfl_xor(p, 8);
            if ((lane & 15) == 0) atomicAdd(&r[b0 + rl], p * QS);
        }
}

extern "C" void kernel_launch(void* const* d_in, const int* in_sizes, int n_in,
                              void* d_out, int out_size, void* d_ws, size_t ws_size,
                              hipStream_t stream)
{
    const int*   x        = (const int*)d_in[0];
    const float* userVecs = (const float*)d_in[1];
    const float* itemVecs = (const float*)d_in[2];
    const float* tagU     = (const float*)d_in[3];
    const float* tagI     = (const float*)d_in[4];
    const float* Watt     = (const float*)d_in[5];
    const float* batt     = (const float*)d_in[6];
    const float* Wmap     = (const float*)d_in[7];
    const float* bmap     = (const float*)d_in[8];

    const int B  = in_sizes[0] / XROW;       // 16384
    const int NT = in_sizes[3] / KDIM;       // 50000

    // ws layout:
    unsigned short* Wattb  = (unsigned short*)d_ws;               // 256*256 bf16
    unsigned short* Wfoldb = Wattb + KDIM * KDIM;                 // 256*768 bf16
    unsigned short* zA     = Wfoldb + KDIM * KFOLD;               // B*768 bf16
    unsigned int*   comb32 = (unsigned int*)(zA + (size_t)B * KFOLD); // NT*128 dw
    float* r = (float*)d_out;

    cvt_kernel<<<(KDIM * KDIM / 4 + 255) / 256, 256, 0, stream>>>(Watt, Wattb,
                                                                  KDIM * KDIM / 4);
    fold_kernel<<<KDIM * KFOLD / 256, 256, 0, stream>>>(Wmap, Wfoldb);

    dim3 gA((NT + 127) / 128, 2);
    tagh_mfma_kernel<<<gA, 256, 0, stream>>>(tagU, Wattb, batt, comb32, NT);

    attn_kernel<<<B / 4, 256, 0, stream>>>(x, userVecs, itemVecs, tagI,
                                           comb32, zA, r);

    dim3 gC(B / 128, 2);
    mix_mfma_kernel<<<gC, 256, 0, stream>>>(zA, Wfoldb, bmap, x, comb32, r, B);
}

// Round 8
// 171.701 us; speedup vs baseline: 1.0095x; 1.0095x over previous
//
#include <hip/hip_runtime.h>

// AttentionPITF: B=16384, K=256, M=50.
// Round 8:
//  - attn reverted to R5 inner loop (VGPR ~56) + split each row across TWO
//    waves (25 m's each, LDS combine): serial chain halves, 2x rows in
//    flight. Epilogue split between the wave pair.
//  - tagh: BN=256 single block per row-panel -> f32 tagU read + cvt once
//    (was twice); tagU u8 pack unconditional.

#define KDIM 256
#define MHIST 50
#define XROW 54
#define KFOLD 768

#define QS    (1.0f / 2048.0f)   // u8 quant scale
#define QINV  2048.0f

typedef __attribute__((ext_vector_type(8))) short bf16x8;
typedef __attribute__((ext_vector_type(4))) float f32x4;

__device__ __forceinline__ unsigned short f2bf(float f) {
    union { float f; unsigned int i; } v; v.f = f;
    unsigned int x = v.i;
    x += 0x7fffu + ((x >> 16) & 1u);          // RNE
    return (unsigned short)(x >> 16);
}
__device__ __forceinline__ unsigned int pack2bf(float a, float b) {
    return (unsigned int)f2bf(a) | ((unsigned int)f2bf(b) << 16);
}
__device__ __forceinline__ unsigned int quq(float v) {
    int q = (int)rintf(v * QINV) + 128;
    return (unsigned int)(q < 0 ? 0 : (q > 255 ? 255 : q));
}
__device__ __forceinline__ float dot4u8(unsigned int w, const float4& u) {
    return (float)(w & 255u)         * u.x + (float)((w >> 8) & 255u)  * u.y +
           (float)((w >> 16) & 255u) * u.z + (float)(w >> 24)          * u.w;
}
__device__ __forceinline__ void haccu8(float4& hv, unsigned int w, float e) {
    hv.x = fmaf(e, (float)(w & 255u),         hv.x);
    hv.y = fmaf(e, (float)((w >> 8) & 255u),  hv.y);
    hv.z = fmaf(e, (float)((w >> 16) & 255u), hv.z);
    hv.w = fmaf(e, (float)(w >> 24),          hv.w);
}

#define GLOAD16(g, l)                                                        \
    __builtin_amdgcn_global_load_lds(                                        \
        (const __attribute__((address_space(1))) void*)(g),                  \
        (__attribute__((address_space(3))) void*)(l), 16, 0, 0)

__device__ __forceinline__ f32x4 mfma16(bf16x8 a, bf16x8 b, f32x4 c) {
    return __builtin_amdgcn_mfma_f32_16x16x32_bf16(a, b, c, 0, 0, 0);
}

// ---------------- prep ----------------------------------------------------
__global__ __launch_bounds__(256) void cvt_kernel(
    const float* __restrict__ src, unsigned short* __restrict__ dst, int n4)
{
    int i = blockIdx.x * 256 + threadIdx.x;
    if (i >= n4) return;
    float4 v = ((const float4*)src)[i];
    ushort4 o;
    o.x = f2bf(v.x); o.y = f2bf(v.y); o.z = f2bf(v.z); o.w = f2bf(v.w);
    ((ushort4*)dst)[i] = o;
}

// Wfold[j][0:256]=W1+W3, [256:512]=W2-W3, [512:768]=W4  (from W_map[j][1024])
__global__ __launch_bounds__(256) void fold_kernel(
    const float* __restrict__ Wmap, unsigned short* __restrict__ Wf)
{
    int idx = blockIdx.x * 256 + threadIdx.x;   // < 256*768
    int j = idx / KFOLD, c = idx % KFOLD;
    int seg = c >> 8, k = c & 255;
    const float* row = Wmap + (size_t)j * 1024;
    float f;
    if (seg == 0)      f = row[k]       + row[512 + k];
    else if (seg == 1) f = row[256 + k] - row[512 + k];
    else               f = row[768 + k];
    Wf[idx] = f2bf(f);
}

// ---------------- Kernel A: tagH = relu(tagU @ W_att^T + b_att) -----------
// BN=256 in one block: A (f32 tagU) read+cvt once; u8 tagU pack here too.
__global__ __launch_bounds__(256) void tagh_mfma_kernel(
    const float* __restrict__ tagU,          // f32 [NT][256]
    const unsigned short* __restrict__ Bb,   // W_att bf16 [256][256]
    const float* __restrict__ batt,
    unsigned int* __restrict__ comb32,       // [NT][128] dwords
    int NT)
{
    __shared__ unsigned short As[128 * 32];
    __shared__ unsigned short Bs[256 * 32];
    const int tid = threadIdx.x;
    const int lane = tid & 63, wave = tid >> 6;
    const int wr = wave >> 1, wc = wave & 1;
    const int m0 = blockIdx.x * 128;
    const int r = tid >> 1, kh = tid & 1;

    const int gm  = m0 + r;
    const int gmc = gm < NT ? gm : NT - 1;
    const float* arow = tagU + (size_t)gmc * KDIM + kh * 16;

    f32x4 acc[4][8] = {};

    for (int k0 = 0; k0 < KDIM; k0 += 32) {
        // B: 256 rows x 32 k bf16 via global_load_lds
#pragma unroll
        for (int p = 0; p < 4; ++p) {
            int s = tid + p * 256;
            int row = s >> 2, ch = s & 3;
            GLOAD16(Bb + ((size_t)row * KDIM + k0 + ch * 8), Bs + s * 8);
        }
        // A: f32 load -> cvt -> ds_write (16 elems/thread)
        const float4 f0 = *(const float4*)(arow + k0);
        const float4 f1 = *(const float4*)(arow + k0 + 4);
        const float4 f2 = *(const float4*)(arow + k0 + 8);
        const float4 f3 = *(const float4*)(arow + k0 + 12);
        uint4 w0, w1;
        w0.x = pack2bf(f0.x, f0.y); w0.y = pack2bf(f0.z, f0.w);
        w0.z = pack2bf(f1.x, f1.y); w0.w = pack2bf(f1.z, f1.w);
        w1.x = pack2bf(f2.x, f2.y); w1.y = pack2bf(f2.z, f2.w);
        w1.z = pack2bf(f3.x, f3.y); w1.w = pack2bf(f3.z, f3.w);
        *(uint4*)&As[r * 32 + kh * 16]     = w0;
        *(uint4*)&As[r * 32 + kh * 16 + 8] = w1;
        if (gm < NT) {
            const int cb = (k0 >> 2) + kh * 4;
            unsigned int* cp = comb32 + (size_t)gm * 128;
            cp[(cb + 0) * 2 + 1] = quq(f0.x) | (quq(f0.y) << 8) |
                                   (quq(f0.z) << 16) | (quq(f0.w) << 24);
            cp[(cb + 1) * 2 + 1] = quq(f1.x) | (quq(f1.y) << 8) |
                                   (quq(f1.z) << 16) | (quq(f1.w) << 24);
            cp[(cb + 2) * 2 + 1] = quq(f2.x) | (quq(f2.y) << 8) |
                                   (quq(f2.z) << 16) | (quq(f2.w) << 24);
            cp[(cb + 3) * 2 + 1] = quq(f3.x) | (quq(f3.y) << 8) |
                                   (quq(f3.z) << 16) | (quq(f3.w) << 24);
        }
        __syncthreads();
        bf16x8 af[4], bg[8];
#pragma unroll
        for (int m = 0; m < 4; ++m) {
            int ar = wr * 64 + m * 16 + (lane & 15);
            af[m] = *(const bf16x8*)&As[ar * 32 + (lane >> 4) * 8];
        }
#pragma unroll
        for (int n = 0; n < 8; ++n) {
            int br = wc * 128 + n * 16 + (lane & 15);
            bg[n] = *(const bf16x8*)&Bs[br * 32 + (lane >> 4) * 8];
        }
#pragma unroll
        for (int m = 0; m < 4; ++m)
#pragma unroll
            for (int n = 0; n < 8; ++n)
                acc[m][n] = mfma16(af[m], bg[n], acc[m][n]);
        __syncthreads();
    }

    unsigned char* comb = (unsigned char*)comb32;
#pragma unroll
    for (int n = 0; n < 8; ++n) {
        int col = wc * 128 + n * 16 + (lane & 15);
        float bias = batt[col];
        int boff = 8 * (col >> 2) + (col & 3);
#pragma unroll
        for (int m = 0; m < 4; ++m)
#pragma unroll
            for (int rr = 0; rr < 4; ++rr) {
                int grow = m0 + wr * 64 + m * 16 + (lane >> 4) * 4 + rr;
                if (grow < NT)
                    comb[(size_t)grow * 512 + boff] =
                        (unsigned char)quq(fmaxf(acc[m][n][rr] + bias, 0.f));
            }
    }
}

// ---------------- Kernel B: per-row attention, TWO waves per row ----------
// Wave pair (2p, 2p+1) owns row b = blockIdx.x*2+p; half=wave&1 covers 25
// m's. Partial h4/ssum combined via LDS + one barrier. R5 inner loop.
__global__ __launch_bounds__(256) void attn_kernel(
    const int* __restrict__ x,
    const float* __restrict__ userVecs,
    const float* __restrict__ itemVecs,
    const float* __restrict__ tagI,
    const unsigned int* __restrict__ comb32,  // [NT][128] dwords
    unsigned short* __restrict__ zA,          // [B][768] bf16: u, h, u*h
    float* __restrict__ r)
{
    const int tid  = threadIdx.x;
    const int wave = tid >> 6, lane = tid & 63;
    const int pair = wave >> 1, half = wave & 1;
    const int b    = blockIdx.x * 2 + pair;

    __shared__ float sh[4][64][4];
    __shared__ float ss[4];

    const int xv = x[(size_t)b * XROW + (lane < XROW ? lane : XROW - 1)];
    const int x0 = __shfl(xv, 0), x1 = __shfl(xv, 1);
    const int x2 = __shfl(xv, 2), x3 = __shfl(xv, 3);

    const float4 u4 = *(const float4*)&userVecs[(size_t)x0 * KDIM + lane * 4];

    // 25 m's per wave, online (max-free) softmax accumulation
    float4 h4 = make_float4(0.f, 0.f, 0.f, 0.f);
    float ssum = 0.f;
#pragma unroll 5
    for (int mm = 0; mm < 25; ++mm) {
        const int m = half * 25 + mm;
        const int t = __shfl(xv, 4 + m);
        const uint2 cv = ((const uint2*)(comb32 + (size_t)t * 128))[lane];
        float d = dot4u8(cv.x, u4);
#pragma unroll
        for (int off = 32; off >= 1; off >>= 1) d += __shfl_xor(d, off);
        const float e = __expf(d * QS);
        ssum += e;
        haccu8(h4, cv.y, e);
    }

    // combine the two halves of this row
    *(float4*)&sh[wave][lane][0] = h4;
    if (lane == 0) ss[wave] = ssum;
    __syncthreads();
    const float4 oh = *(const float4*)&sh[wave ^ 1][lane][0];
    h4.x += oh.x; h4.y += oh.y; h4.z += oh.z; h4.w += oh.w;
    ssum = ss[pair * 2] + ss[pair * 2 + 1];

    const float sc = QS / ssum;
    const float c128 = 128.0f * QS;
    h4.x = h4.x * sc - c128;
    h4.y = h4.y * sc - c128;
    h4.z = h4.z * sc - c128;
    h4.w = h4.w * sc - c128;

    const size_t zb = (size_t)b * KFOLD + lane * 4;
    if (half == 0) {
        // z segments 0 (u) and 1 (h)
        ushort4 o;
        o.x = f2bf(u4.x); o.y = f2bf(u4.y); o.z = f2bf(u4.z); o.w = f2bf(u4.w);
        *(ushort4*)&zA[zb] = o;
        o.x = f2bf(h4.x); o.y = f2bf(h4.y); o.z = f2bf(h4.z); o.w = f2bf(h4.w);
        *(ushort4*)&zA[zb + 256] = o;
    } else {
        // z segment 2 (u*h)
        ushort4 o;
        o.x = f2bf(u4.x * h4.x); o.y = f2bf(u4.y * h4.y);
        o.z = f2bf(u4.z * h4.z); o.w = f2bf(u4.w * h4.w);
        *(ushort4*)&zA[zb + 512] = o;
        // r[b] = iv . (it - nit)   (all f32)
        const float4 iv  = *(const float4*)&itemVecs[(size_t)x1 * KDIM + lane * 4];
        const float4 itv = *(const float4*)&tagI[(size_t)x2 * KDIM + lane * 4];
        const float4 niv = *(const float4*)&tagI[(size_t)x3 * KDIM + lane * 4];
        float part = iv.x * (itv.x - niv.x) + iv.y * (itv.y - niv.y) +
                     iv.z * (itv.z - niv.z) + iv.w * (itv.w - niv.w);
#pragma unroll
        for (int off = 32; off >= 1; off >>= 1) part += __shfl_xor(part, off);
        if (lane == 0) r[b] = part;
    }
}

// ---------------- Kernel C: mix GEMM (bf16 MFMA) + fused dot --------------
__global__ __launch_bounds__(256) void mix_mfma_kernel(
    const unsigned short* __restrict__ Zb,   // [B][768] bf16
    const unsigned short* __restrict__ Wf,   // [256][768] bf16
    const float* __restrict__ bmap,
    const int* __restrict__ x,
    const unsigned int* __restrict__ comb32, // u8 table for ut/nut epilogue
    float* __restrict__ r,
    int Bn)
{
    __shared__ unsigned short As[128 * 32];
    __shared__ unsigned short Bs[128 * 32];
    __shared__ int xr2s[128], xr3s[128];

    const int tid = threadIdx.x;
    const int lane = tid & 63, wave = tid >> 6;
    const int wr = wave >> 1, wc = wave & 1;
    const int b0 = blockIdx.x * 128, n0 = blockIdx.y * 128;

    if (tid < 128) {
        int gb = b0 + tid;
        xr2s[tid] = x[(size_t)gb * XROW + 2];
        xr3s[tid] = x[(size_t)gb * XROW + 3];
    }

    f32x4 acc[4][4] = {};

    for (int k0 = 0; k0 < KFOLD; k0 += 32) {
#pragma unroll
        for (int p = 0; p < 2; ++p) {
            int s = tid + p * 256;
            int row = s >> 2, ch = s & 3;
            GLOAD16(Zb + ((size_t)(b0 + row) * KFOLD + k0 + ch * 8), As + s * 8);
            GLOAD16(Wf + ((size_t)(n0 + row) * KFOLD + k0 + ch * 8), Bs + s * 8);
        }
        __syncthreads();
        bf16x8 af[4], bg[4];
#pragma unroll
        for (int m = 0; m < 4; ++m) {
            int ar = wr * 64 + m * 16 + (lane & 15);
            af[m] = *(const bf16x8*)&As[ar * 32 + (lane >> 4) * 8];
        }
#pragma unroll
        for (int n = 0; n < 4; ++n) {
            int br = wc * 64 + n * 16 + (lane & 15);
            bg[n] = *(const bf16x8*)&Bs[br * 32 + (lane >> 4) * 8];
        }
#pragma unroll
        for (int m = 0; m < 4; ++m)
#pragma unroll
            for (int n = 0; n < 4; ++n)
                acc[m][n] = mfma16(af[m], bg[n], acc[m][n]);
        __syncthreads();
    }

    const unsigned char* comb = (const unsigned char*)comb32;
    int   offn[4];
    float bias[4];
#pragma unroll
    for (int n = 0; n < 4; ++n) {
        int col = n0 + wc * 64 + n * 16 + (lane & 15);
        bias[n] = bmap[col];
        offn[n] = 8 * (col >> 2) + 4 + (col & 3);   // u8 tagU byte in comb row
    }
#pragma unroll
    for (int m = 0; m < 4; ++m)
#pragma unroll
        for (int rr = 0; rr < 4; ++rr) {
            int rl = wr * 64 + m * 16 + (lane >> 4) * 4 + rr;
            const unsigned char* utp = comb + (size_t)xr2s[rl] * 512;
            const unsigned char* ntp = comb + (size_t)xr3s[rl] * 512;
            float p = 0.f;
#pragma unroll
            for (int n = 0; n < 4; ++n) {
                float mixv = fmaxf(acc[m][n][rr] + bias[n], 0.f);
                p += mixv * (float)((int)utp[offn[n]] - (int)ntp[offn[n]]);
            }
            p += __shfl_xor(p, 1);
            p += __shfl_xor(p, 2);
            p += __shfl_xor(p, 4);
            p += __shfl_xor(p, 8);
            if ((lane & 15) == 0) atomicAdd(&r[b0 + rl], p * QS);
        }
}

extern "C" void kernel_launch(void* const* d_in, const int* in_sizes, int n_in,
                              void* d_out, int out_size, void* d_ws, size_t ws_size,
                              hipStream_t stream)
{
    const int*   x        = (const int*)d_in[0];
    const float* userVecs = (const float*)d_in[1];
    const float* itemVecs = (const float*)d_in[2];
    const float* tagU     = (const float*)d_in[3];
    const float* tagI     = (const float*)d_in[4];
    const float* Watt     = (const float*)d_in[5];
    const float* batt     = (const float*)d_in[6];
    const float* Wmap     = (const float*)d_in[7];
    const float* bmap     = (const float*)d_in[8];

    const int B  = in_sizes[0] / XROW;       // 16384
    const int NT = in_sizes[3] / KDIM;       // 50000

    // ws layout:
    unsigned short* Wattb  = (unsigned short*)d_ws;               // 256*256 bf16
    unsigned short* Wfoldb = Wattb + KDIM * KDIM;                 // 256*768 bf16
    unsigned short* zA     = Wfoldb + KDIM * KFOLD;               // B*768 bf16
    unsigned int*   comb32 = (unsigned int*)(zA + (size_t)B * KFOLD); // NT*128 dw
    float* r = (float*)d_out;

    cvt_kernel<<<(KDIM * KDIM / 4 + 255) / 256, 256, 0, stream>>>(Watt, Wattb,
                                                                  KDIM * KDIM / 4);
    fold_kernel<<<KDIM * KFOLD / 256, 256, 0, stream>>>(Wmap, Wfoldb);

    dim3 gA((NT + 127) / 128);
    tagh_mfma_kernel<<<gA, 256, 0, stream>>>(tagU, Wattb, batt, comb32, NT);

    attn_kernel<<<B / 2, 256, 0, stream>>>(x, userVecs, itemVecs, tagI,
                                           comb32, zA, r);

    dim3 gC(B / 128, 2);
    mix_mfma_kernel<<<gC, 256, 0, stream>>>(zA, Wfoldb, bmap, x, comb32, r, B);
}

// Round 9
// 139.738 us; speedup vs baseline: 1.2404x; 1.2287x over previous
//
#include <hip/hip_runtime.h>

// AttentionPITF: B=16384, K=256, M=50.
// Round 9: fix tagh regression from R8.
//  - comb row layout changed to HALF-SPLIT: [0:256]=tagH u8, [256:512]=tagU u8
//    (was 8B-interleaved chunks -> stride-8 byte stores, 2x write amplification).
//  - tagh back to 128x128 tiles (grid 391x2, VGPR ~104); tagU pack is one
//    contiguous uint4 store; tagH epilogue staged in LDS (reuse As/Bs) then
//    written as coalesced dwordx4.
//  - attn: two independent dword gathers per (row,m); 2 waves per row (R8).
//  - mix epilogue: tagU u8 byte at offset 256+col.

#define KDIM 256
#define MHIST 50
#define XROW 54
#define KFOLD 768

#define QS    (1.0f / 2048.0f)   // u8 quant scale
#define QINV  2048.0f

typedef __attribute__((ext_vector_type(8))) short bf16x8;
typedef __attribute__((ext_vector_type(4))) float f32x4;

__device__ __forceinline__ unsigned short f2bf(float f) {
    union { float f; unsigned int i; } v; v.f = f;
    unsigned int x = v.i;
    x += 0x7fffu + ((x >> 16) & 1u);          // RNE
    return (unsigned short)(x >> 16);
}
__device__ __forceinline__ unsigned int pack2bf(float a, float b) {
    return (unsigned int)f2bf(a) | ((unsigned int)f2bf(b) << 16);
}
__device__ __forceinline__ unsigned int quq(float v) {
    int q = (int)rintf(v * QINV) + 128;
    return (unsigned int)(q < 0 ? 0 : (q > 255 ? 255 : q));
}
__device__ __forceinline__ float dot4u8(unsigned int w, const float4& u) {
    return (float)(w & 255u)         * u.x + (float)((w >> 8) & 255u)  * u.y +
           (float)((w >> 16) & 255u) * u.z + (float)(w >> 24)          * u.w;
}
__device__ __forceinline__ void haccu8(float4& hv, unsigned int w, float e) {
    hv.x = fmaf(e, (float)(w & 255u),         hv.x);
    hv.y = fmaf(e, (float)((w >> 8) & 255u),  hv.y);
    hv.z = fmaf(e, (float)((w >> 16) & 255u), hv.z);
    hv.w = fmaf(e, (float)(w >> 24),          hv.w);
}

#define GLOAD16(g, l)                                                        \
    __builtin_amdgcn_global_load_lds(                                        \
        (const __attribute__((address_space(1))) void*)(g),                  \
        (__attribute__((address_space(3))) void*)(l), 16, 0, 0)

__device__ __forceinline__ f32x4 mfma16(bf16x8 a, bf16x8 b, f32x4 c) {
    return __builtin_amdgcn_mfma_f32_16x16x32_bf16(a, b, c, 0, 0, 0);
}

// ---------------- prep ----------------------------------------------------
__global__ __launch_bounds__(256) void cvt_kernel(
    const float* __restrict__ src, unsigned short* __restrict__ dst, int n4)
{
    int i = blockIdx.x * 256 + threadIdx.x;
    if (i >= n4) return;
    float4 v = ((const float4*)src)[i];
    ushort4 o;
    o.x = f2bf(v.x); o.y = f2bf(v.y); o.z = f2bf(v.z); o.w = f2bf(v.w);
    ((ushort4*)dst)[i] = o;
}

// Wfold[j][0:256]=W1+W3, [256:512]=W2-W3, [512:768]=W4  (from W_map[j][1024])
__global__ __launch_bounds__(256) void fold_kernel(
    const float* __restrict__ Wmap, unsigned short* __restrict__ Wf)
{
    int idx = blockIdx.x * 256 + threadIdx.x;   // < 256*768
    int j = idx / KFOLD, c = idx % KFOLD;
    int seg = c >> 8, k = c & 255;
    const float* row = Wmap + (size_t)j * 1024;
    float f;
    if (seg == 0)      f = row[k]       + row[512 + k];
    else if (seg == 1) f = row[256 + k] - row[512 + k];
    else               f = row[768 + k];
    Wf[idx] = f2bf(f);
}

// ---------------- Kernel A: tagH = relu(tagU @ W_att^T + b_att) -----------
// 128x128 tile, grid (391, 2). A staged from f32 tagU (in-kernel cvt).
// Panel 0 also packs tagU u8 (one uint4/thread/K-step, contiguous).
// tagH epilogue: quantize -> LDS stage (16KB, reuses As/Bs) -> dwordx4.
__global__ __launch_bounds__(256) void tagh_mfma_kernel(
    const float* __restrict__ tagU,          // f32 [NT][256]
    const unsigned short* __restrict__ Bb,   // W_att bf16 [256][256]
    const float* __restrict__ batt,
    unsigned int* __restrict__ comb32,       // [NT][128] dw: 64 tagH | 64 tagU
    int NT)
{
    __shared__ unsigned char smem[20480];
    unsigned short* As = (unsigned short*)smem;            // 128*32 bf16 (8KB)
    unsigned short* Bs = (unsigned short*)(smem + 8192);   // 128*32 bf16 (8KB)
    unsigned char*  comb = (unsigned char*)comb32;

    const int tid = threadIdx.x;
    const int lane = tid & 63, wave = tid >> 6;
    const int wr = wave >> 1, wc = wave & 1;
    const int m0 = blockIdx.x * 128;
    const int n0 = blockIdx.y * 128;
    const int r = tid >> 1, kh = tid & 1;

    const int gm  = m0 + r;
    const int gmc = gm < NT ? gm : NT - 1;
    const float* arow = tagU + (size_t)gmc * KDIM + kh * 16;

    f32x4 acc[4][4] = {};

    for (int k0 = 0; k0 < KDIM; k0 += 32) {
        // B: global_load_lds (bf16)
#pragma unroll
        for (int p = 0; p < 2; ++p) {
            int s = tid + p * 256;
            int row = s >> 2, ch = s & 3;
            GLOAD16(Bb + ((size_t)(n0 + row) * KDIM + k0 + ch * 8), Bs + s * 8);
        }
        // A: f32 load -> cvt -> ds_write (16 elems/thread)
        const float4 f0 = *(const float4*)(arow + k0);
        const float4 f1 = *(const float4*)(arow + k0 + 4);
        const float4 f2 = *(const float4*)(arow + k0 + 8);
        const float4 f3 = *(const float4*)(arow + k0 + 12);
        uint4 w0, w1;
        w0.x = pack2bf(f0.x, f0.y); w0.y = pack2bf(f0.z, f0.w);
        w0.z = pack2bf(f1.x, f1.y); w0.w = pack2bf(f1.z, f1.w);
        w1.x = pack2bf(f2.x, f2.y); w1.y = pack2bf(f2.z, f2.w);
        w1.z = pack2bf(f3.x, f3.y); w1.w = pack2bf(f3.z, f3.w);
        *(uint4*)&As[r * 32 + kh * 16]     = w0;
        *(uint4*)&As[r * 32 + kh * 16 + 8] = w1;
        if (n0 == 0 && gm < NT) {
            // tagU u8: cols k0+kh*16 .. +15 -> bytes 256+k0+kh*16, one uint4
            uint4 qv;
            qv.x = quq(f0.x) | (quq(f0.y) << 8) | (quq(f0.z) << 16) | (quq(f0.w) << 24);
            qv.y = quq(f1.x) | (quq(f1.y) << 8) | (quq(f1.z) << 16) | (quq(f1.w) << 24);
            qv.z = quq(f2.x) | (quq(f2.y) << 8) | (quq(f2.z) << 16) | (quq(f2.w) << 24);
            qv.w = quq(f3.x) | (quq(f3.y) << 8) | (quq(f3.z) << 16) | (quq(f3.w) << 24);
            *(uint4*)(comb + (size_t)gm * 512 + 256 + k0 + kh * 16) = qv;
        }
        __syncthreads();
        bf16x8 af[4], bg[4];
#pragma unroll
        for (int m = 0; m < 4; ++m) {
            int ar = wr * 64 + m * 16 + (lane & 15);
            af[m] = *(const bf16x8*)&As[ar * 32 + (lane >> 4) * 8];
        }
#pragma unroll
        for (int n = 0; n < 4; ++n) {
            int br = wc * 64 + n * 16 + (lane & 15);
            bg[n] = *(const bf16x8*)&Bs[br * 32 + (lane >> 4) * 8];
        }
#pragma unroll
        for (int m = 0; m < 4; ++m)
#pragma unroll
            for (int n = 0; n < 4; ++n)
                acc[m][n] = mfma16(af[m], bg[n], acc[m][n]);
        __syncthreads();
    }

    // epilogue: quantize tagH into LDS stage (128 rows x 128 cols u8),
    // then write coalesced dwordx4 into comb[row][n0 .. n0+127].
    unsigned char* stage = smem;              // 16KB, As/Bs done
#pragma unroll
    for (int n = 0; n < 4; ++n) {
        int colL = wc * 64 + n * 16 + (lane & 15);
        float bias = batt[n0 + colL];
#pragma unroll
        for (int m = 0; m < 4; ++m)
#pragma unroll
            for (int rr = 0; rr < 4; ++rr) {
                int rowL = wr * 64 + m * 16 + (lane >> 4) * 4 + rr;
                stage[rowL * 128 + colL] =
                    (unsigned char)quq(fmaxf(acc[m][n][rr] + bias, 0.f));
            }
    }
    __syncthreads();
    {
        const int rowL = tid >> 1, half = tid & 1;
        const int grow = m0 + rowL;
        if (grow < NT) {
            const uint4* src = (const uint4*)(stage + rowL * 128 + half * 64);
            uint4* dst = (uint4*)(comb + (size_t)grow * 512 + n0 + half * 64);
            dst[0] = src[0]; dst[1] = src[1]; dst[2] = src[2]; dst[3] = src[3];
        }
    }
}

// ---------------- Kernel B: per-row attention, TWO waves per row ----------
// Wave pair (2p, 2p+1) owns row b = blockIdx.x*2+p; half=wave&1 covers 25
// m's. Partial h4/ssum combined via LDS + one barrier.
__global__ __launch_bounds__(256) void attn_kernel(
    const int* __restrict__ x,
    const float* __restrict__ userVecs,
    const float* __restrict__ itemVecs,
    const float* __restrict__ tagI,
    const unsigned int* __restrict__ comb32,  // [NT][128] dw: 64 tagH | 64 tagU
    unsigned short* __restrict__ zA,          // [B][768] bf16: u, h, u*h
    float* __restrict__ r)
{
    const int tid  = threadIdx.x;
    const int wave = tid >> 6, lane = tid & 63;
    const int pair = wave >> 1, half = wave & 1;
    const int b    = blockIdx.x * 2 + pair;

    __shared__ float sh[4][64][4];
    __shared__ float ss[4];

    const int xv = x[(size_t)b * XROW + (lane < XROW ? lane : XROW - 1)];
    const int x0 = __shfl(xv, 0), x1 = __shfl(xv, 1);
    const int x2 = __shfl(xv, 2), x3 = __shfl(xv, 3);

    const float4 u4 = *(const float4*)&userVecs[(size_t)x0 * KDIM + lane * 4];

    // 25 m's per wave, online (max-free) softmax accumulation
    float4 h4 = make_float4(0.f, 0.f, 0.f, 0.f);
    float ssum = 0.f;
#pragma unroll 5
    for (int mm = 0; mm < 25; ++mm) {
        const int m = half * 25 + mm;
        const int t = __shfl(xv, 4 + m);
        const unsigned int hq = comb32[(size_t)t * 128 + lane];
        const unsigned int uq = comb32[(size_t)t * 128 + 64 + lane];
        float d = dot4u8(hq, u4);
#pragma unroll
        for (int off = 32; off >= 1; off >>= 1) d += __shfl_xor(d, off);
        const float e = __expf(d * QS);
        ssum += e;
        haccu8(h4, uq, e);
    }

    // combine the two halves of this row
    *(float4*)&sh[wave][lane][0] = h4;
    if (lane == 0) ss[wave] = ssum;
    __syncthreads();
    const float4 oh = *(const float4*)&sh[wave ^ 1][lane][0];
    h4.x += oh.x; h4.y += oh.y; h4.z += oh.z; h4.w += oh.w;
    ssum = ss[pair * 2] + ss[pair * 2 + 1];

    const float sc = QS / ssum;
    const float c128 = 128.0f * QS;
    h4.x = h4.x * sc - c128;
    h4.y = h4.y * sc - c128;
    h4.z = h4.z * sc - c128;
    h4.w = h4.w * sc - c128;

    const size_t zb = (size_t)b * KFOLD + lane * 4;
    if (half == 0) {
        // z segments 0 (u) and 1 (h)
        ushort4 o;
        o.x = f2bf(u4.x); o.y = f2bf(u4.y); o.z = f2bf(u4.z); o.w = f2bf(u4.w);
        *(ushort4*)&zA[zb] = o;
        o.x = f2bf(h4.x); o.y = f2bf(h4.y); o.z = f2bf(h4.z); o.w = f2bf(h4.w);
        *(ushort4*)&zA[zb + 256] = o;
    } else {
        // z segment 2 (u*h)
        ushort4 o;
        o.x = f2bf(u4.x * h4.x); o.y = f2bf(u4.y * h4.y);
        o.z = f2bf(u4.z * h4.z); o.w = f2bf(u4.w * h4.w);
        *(ushort4*)&zA[zb + 512] = o;
        // r[b] = iv . (it - nit)   (all f32)
        const float4 iv  = *(const float4*)&itemVecs[(size_t)x1 * KDIM + lane * 4];
        const float4 itv = *(const float4*)&tagI[(size_t)x2 * KDIM + lane * 4];
        const float4 niv = *(const float4*)&tagI[(size_t)x3 * KDIM + lane * 4];
        float part = iv.x * (itv.x - niv.x) + iv.y * (itv.y - niv.y) +
                     iv.z * (itv.z - niv.z) + iv.w * (itv.w - niv.w);
#pragma unroll
        for (int off = 32; off >= 1; off >>= 1) part += __shfl_xor(part, off);
        if (lane == 0) r[b] = part;
    }
}

// ---------------- Kernel C: mix GEMM (bf16 MFMA) + fused dot --------------
__global__ __launch_bounds__(256) void mix_mfma_kernel(
    const unsigned short* __restrict__ Zb,   // [B][768] bf16
    const unsigned short* __restrict__ Wf,   // [256][768] bf16
    const float* __restrict__ bmap,
    const int* __restrict__ x,
    const unsigned int* __restrict__ comb32, // u8 table for ut/nut epilogue
    float* __restrict__ r,
    int Bn)
{
    __shared__ unsigned short As[128 * 32];
    __shared__ unsigned short Bs[128 * 32];
    __shared__ int xr2s[128], xr3s[128];

    const int tid = threadIdx.x;
    const int lane = tid & 63, wave = tid >> 6;
    const int wr = wave >> 1, wc = wave & 1;
    const int b0 = blockIdx.x * 128, n0 = blockIdx.y * 128;

    if (tid < 128) {
        int gb = b0 + tid;
        xr2s[tid] = x[(size_t)gb * XROW + 2];
        xr3s[tid] = x[(size_t)gb * XROW + 3];
    }

    f32x4 acc[4][4] = {};

    for (int k0 = 0; k0 < KFOLD; k0 += 32) {
#pragma unroll
        for (int p = 0; p < 2; ++p) {
            int s = tid + p * 256;
            int row = s >> 2, ch = s & 3;
            GLOAD16(Zb + ((size_t)(b0 + row) * KFOLD + k0 + ch * 8), As + s * 8);
            GLOAD16(Wf + ((size_t)(n0 + row) * KFOLD + k0 + ch * 8), Bs + s * 8);
        }
        __syncthreads();
        bf16x8 af[4], bg[4];
#pragma unroll
        for (int m = 0; m < 4; ++m) {
            int ar = wr * 64 + m * 16 + (lane & 15);
            af[m] = *(const bf16x8*)&As[ar * 32 + (lane >> 4) * 8];
        }
#pragma unroll
        for (int n = 0; n < 4; ++n) {
            int br = wc * 64 + n * 16 + (lane & 15);
            bg[n] = *(const bf16x8*)&Bs[br * 32 + (lane >> 4) * 8];
        }
#pragma unroll
        for (int m = 0; m < 4; ++m)
#pragma unroll
            for (int n = 0; n < 4; ++n)
                acc[m][n] = mfma16(af[m], bg[n], acc[m][n]);
        __syncthreads();
    }

    const unsigned char* comb = (const unsigned char*)comb32;
    int   offn[4];
    float bias[4];
#pragma unroll
    for (int n = 0; n < 4; ++n) {
        int col = n0 + wc * 64 + n * 16 + (lane & 15);
        bias[n] = bmap[col];
        offn[n] = 256 + col;                 // tagU u8 byte in comb row
    }
#pragma unroll
    for (int m = 0; m < 4; ++m)
#pragma unroll
        for (int rr = 0; rr < 4; ++rr) {
            int rl = wr * 64 + m * 16 + (lane >> 4) * 4 + rr;
            const unsigned char* utp = comb + (size_t)xr2s[rl] * 512;
            const unsigned char* ntp = comb + (size_t)xr3s[rl] * 512;
            float p = 0.f;
#pragma unroll
            for (int n = 0; n < 4; ++n) {
                float mixv = fmaxf(acc[m][n][rr] + bias[n], 0.f);
                p += mixv * (float)((int)utp[offn[n]] - (int)ntp[offn[n]]);
            }
            p += __shfl_xor(p, 1);
            p += __shfl_xor(p, 2);
            p += __shfl_xor(p, 4);
            p += __shfl_xor(p, 8);
            if ((lane & 15) == 0) atomicAdd(&r[b0 + rl], p * QS);
        }
}

extern "C" void kernel_launch(void* const* d_in, const int* in_sizes, int n_in,
                              void* d_out, int out_size, void* d_ws, size_t ws_size,
                              hipStream_t stream)
{
    const int*   x        = (const int*)d_in[0];
    const float* userVecs = (const float*)d_in[1];
    const float* itemVecs = (const float*)d_in[2];
    const float* tagU     = (const float*)d_in[3];
    const float* tagI     = (const float*)d_in[4];
    const float* Watt     = (const float*)d_in[5];
    const float* batt     = (const float*)d_in[6];
    const float* Wmap     = (const float*)d_in[7];
    const float* bmap     = (const float*)d_in[8];

    const int B  = in_sizes[0] / XROW;       // 16384
    const int NT = in_sizes[3] / KDIM;       // 50000

    // ws layout:
    unsigned short* Wattb  = (unsigned short*)d_ws;               // 256*256 bf16
    unsigned short* Wfoldb = Wattb + KDIM * KDIM;                 // 256*768 bf16
    unsigned short* zA     = Wfoldb + KDIM * KFOLD;               // B*768 bf16
    unsigned int*   comb32 = (unsigned int*)(zA + (size_t)B * KFOLD); // NT*128 dw
    float* r = (float*)d_out;

    cvt_kernel<<<(KDIM * KDIM / 4 + 255) / 256, 256, 0, stream>>>(Watt, Wattb,
                                                                  KDIM * KDIM / 4);
    fold_kernel<<<KDIM * KFOLD / 256, 256, 0, stream>>>(Wmap, Wfoldb);

    dim3 gA((NT + 127) / 128, 2);
    tagh_mfma_kernel<<<gA, 256, 0, stream>>>(tagU, Wattb, batt, comb32, NT);

    attn_kernel<<<B / 2, 256, 0, stream>>>(x, userVecs, itemVecs, tagI,
                                           comb32, zA, r);

    dim3 gC(B / 128, 2);
    mix_mfma_kernel<<<gC, 256, 0, stream>>>(zA, Wfoldb, bmap, x, comb32, r, B);
}